// Round 7
// baseline (1394.498 us; speedup 1.0000x reference)
//
#include <hip/hip_runtime.h>
#include <hip/hip_bf16.h>

#define HID 16
#define NGRAPH 1000
#define NEG_SLOPE 0.2f
#define EPS_GN 1e-5f
#define BSH 11              // bucket shift: 2048 dsts per bucket
#define BS 2048             // bucket span (power of 2)
#define NBMAX 2048
#define CHK 4096            // edges per scatter chunk

typedef __hip_bfloat16 bf16;

static __device__ __forceinline__ float b2f(bf16 v) { return __bfloat162float(v); }

// pack two floats into one u32 holding two RNE-rounded bf16s (a=low, b=high)
static __device__ __forceinline__ unsigned int pack2(float a, float b) {
    unsigned int ia = __float_as_uint(a);
    unsigned int ib = __float_as_uint(b);
    ia += 0x7FFFu + ((ia >> 16) & 1u);
    ib += 0x7FFFu + ((ib >> 16) & 1u);
    return (ia >> 16) | (ib & 0xFFFF0000u);
}

// acc[0..15] += p * bf16row(ra,rb)
static __device__ __forceinline__ void fma_row(const uint4 ra, const uint4 rb, float p,
                                               float* __restrict__ acc) {
    unsigned int us[8] = {ra.x, ra.y, ra.z, ra.w, rb.x, rb.y, rb.z, rb.w};
#pragma unroll
    for (int q = 0; q < 8; ++q) {
        float lo = __uint_as_float(us[q] << 16);
        float hi = __uint_as_float(us[q] & 0xFFFF0000u);
        acc[2 * q]     = fmaf(p, lo, acc[2 * q]);
        acc[2 * q + 1] = fmaf(p, hi, acc[2 * q + 1]);
    }
}

struct PtrPack { const void* src[30]; int cnt[30]; int dstoff[30]; int n; };

// ---------------- dtype detection + param conversion (single block) ----------------
__global__ void detect_cvt(const void* x, const void* ei, int* flags, PtrPack pk,
                           float* __restrict__ dst) {
    __shared__ int cbf, czero;
    __shared__ int isbS;
    int t = threadIdx.x;
    if (t == 0) { cbf = 0; czero = 0; }
    __syncthreads();
    const unsigned int* xw = (const unsigned int*)x;
    unsigned int w = xw[t * 4];
    int e_lo = (int)((w >> 7) & 0xFF);
    if (e_lo >= 100 && e_lo <= 140) atomicAdd(&cbf, 1);
    const unsigned int* ew = (const unsigned int*)ei;
    if (ew[2 * t + 1] == 0u) atomicAdd(&czero, 1);
    __syncthreads();
    if (t == 0) {
        int isb = (cbf >= 192) ? 1 : 0;
        flags[0] = isb;
        flags[1] = (czero >= 250) ? 1 : 0;
        isbS = isb;
    }
    __syncthreads();
    int isb = isbS;
    for (int j = 0; j < pk.n; ++j) {
        const void* s = pk.src[j];
        int c = pk.cnt[j], o = pk.dstoff[j];
        for (int i = t; i < c; i += blockDim.x) {
            float v = isb ? b2f(((const bf16*)s)[i]) : ((const float*)s)[i];
            dst[o + i] = v;
        }
    }
}

static __device__ __forceinline__ int ld_src(const int* ei, int E, int e, int i64) {
    return i64 ? ei[2ll * e] : ei[e];
}
static __device__ __forceinline__ int ld_dst(const int* ei, int E, int e, int i64) {
    return i64 ? ei[2ll * (E + e)] : ei[(long long)E + e];
}

// ---------------- CSR build: two-level bucket counting sort ----------------

__global__ void bucket_count(const int* __restrict__ ei, int E, const int* __restrict__ flags,
                             int* __restrict__ bcnt, int NB) {
    __shared__ int lh[NBMAX];
    int tid = threadIdx.x;
    for (int i = tid; i < NB; i += 256) lh[i] = 0;
    __syncthreads();
    int i64 = flags[1];
    int stride = gridDim.x * 256;
    for (int e = blockIdx.x * 256 + tid; e < E; e += stride)
        atomicAdd(&lh[ld_dst(ei, E, e, i64) >> BSH], 1);
    __syncthreads();
    for (int i = tid; i < NB; i += 256)
        if (lh[i]) atomicAdd(&bcnt[i], lh[i]);
}

__global__ void scan_buckets(const int* __restrict__ bcnt, int NB, int E,
                             int* __restrict__ gBase, int* __restrict__ gCursor,
                             int* __restrict__ rowStart, int N) {
    __shared__ int part[256];
    int t = threadIdx.x;
    int per = (NB + 255) >> 8;
    int lo = t * per, hi = min(lo + per, NB);
    int s = 0;
    for (int i = lo; i < hi; ++i) s += bcnt[i];
    part[t] = s;
    __syncthreads();
    for (int off = 1; off < 256; off <<= 1) {
        int v = (t >= off) ? part[t - off] : 0;
        __syncthreads();
        part[t] += v;
        __syncthreads();
    }
    int acc = (t == 0) ? 0 : part[t - 1];
    for (int i = lo; i < hi; ++i) {
        gBase[i] = acc; gCursor[i] = acc;
        acc += bcnt[i];
    }
    if (t == 0) { gBase[NB] = E; rowStart[N] = E; }
}

__global__ void bucket_scatter(const int* __restrict__ ei, int E, const int* __restrict__ flags,
                               int* __restrict__ gCursor, uint2* __restrict__ binned, int NB) {
    __shared__ int lh[NBMAX];
    __shared__ int lbase[NBMAX];
    __shared__ int lcur[NBMAX];
    int tid = threadIdx.x;
    int i64 = flags[1];
    int nchunk = (E + CHK - 1) / CHK;
    for (int chunk = blockIdx.x; chunk < nchunk; chunk += gridDim.x) {
        int c0 = chunk * CHK;
        int c1 = min(c0 + CHK, E);
        for (int i = tid; i < NB; i += 256) lh[i] = 0;
        __syncthreads();
        for (int e = c0 + tid; e < c1; e += 256)
            atomicAdd(&lh[ld_dst(ei, E, e, i64) >> BSH], 1);
        __syncthreads();
        for (int b = tid; b < NB; b += 256) {
            int c = lh[b];
            lbase[b] = c ? atomicAdd(&gCursor[b], c) : 0;
            lcur[b] = 0;
        }
        __syncthreads();
        for (int e = c0 + tid; e < c1; e += 256) {
            int d = ld_dst(ei, E, e, i64);
            int s = ld_src(ei, E, e, i64);
            int b = d >> BSH;
            int off = atomicAdd(&lcur[b], 1);
            binned[lbase[b] + off] = make_uint2((unsigned)s, (unsigned)(d & (BS - 1)));
        }
        __syncthreads();
    }
}

__global__ void bucket_sort(const uint2* __restrict__ binned, const int* __restrict__ gBase,
                            int* __restrict__ csrSrc, int* __restrict__ rowStart, int N) {
    __shared__ int hist[BS];
    __shared__ int tsum[1024];
    int tid = threadIdx.x;
    int b = blockIdx.x;
    int base = gBase[b];
    int cnt = gBase[b + 1] - base;
    for (int i = tid; i < BS; i += 1024) hist[i] = 0;
    __syncthreads();
    for (int i = tid; i < cnt; i += 1024)
        atomicAdd(&hist[binned[base + i].y], 1);
    __syncthreads();
    int a0 = hist[2 * tid], a1 = hist[2 * tid + 1];
    tsum[tid] = a0 + a1;
    __syncthreads();
    for (int off = 1; off < 1024; off <<= 1) {
        int v = (tid >= off) ? tsum[tid - off] : 0;
        __syncthreads();
        tsum[tid] += v;
        __syncthreads();
    }
    int excl = (tid == 0) ? 0 : tsum[tid - 1];
    int d0 = b * BS + 2 * tid;
    if (d0 < N) rowStart[d0] = base + excl;
    if (d0 + 1 < N) rowStart[d0 + 1] = base + excl + a0;
    __syncthreads();
    hist[2 * tid] = excl;
    hist[2 * tid + 1] = excl + a0;
    __syncthreads();
    for (int i = tid; i < cnt; i += 1024) {
        uint2 pr = binned[base + i];
        int off = atomicAdd(&hist[pr.y], 1);
        csrSrc[base + off] = (int)pr.x;
    }
}

__global__ void graph_cnt_k(const int* __restrict__ batch, int N, float* __restrict__ gcnt) {
    int g = blockIdx.x * blockDim.x + threadIdx.x;
    if (g < NGRAPH) {
        int lo = 0, hi = N;
        while (lo < hi) { int mid = (lo + hi) >> 1; if (batch[mid] < g) lo = mid + 1; else hi = mid; }
        int lb = lo;
        lo = 0; hi = N;
        while (lo < hi) { int mid = (lo + hi) >> 1; if (batch[mid] <= g) lo = mid + 1; else hi = mid; }
        gcnt[g] = (float)(lo - lb);
    }
}

// ---------------- layer-0 node transform (writes bf16-packed h) ----------------
__global__ void node_feat0(const void* __restrict__ xin, int din,
                           const int* __restrict__ flags, const float* __restrict__ prmL,
                           unsigned int* __restrict__ hb, float* __restrict__ as_,
                           float* __restrict__ ad_, int N) {
    __shared__ float sW[256], sa[HID], sd[HID];
    int t = threadIdx.x;
    if (t < din * HID) sW[t] = prmL[t];
    if (t < HID) { sa[t] = prmL[256 + t]; sd[t] = prmL[272 + t]; }
    __syncthreads();
    int i = blockIdx.x * blockDim.x + t;
    if (i >= N) return;
    int isb = flags[0];
    const float* xf = (const float*)xin;
    const bf16* xb = (const bf16*)xin;
    float hr[HID];
#pragma unroll
    for (int j = 0; j < HID; ++j) hr[j] = 0.f;
    int base = i * din;
    for (int k = 0; k < din; ++k) {
        float xv = isb ? b2f(xb[base + k]) : xf[base + k];
#pragma unroll
        for (int j = 0; j < HID; ++j) hr[j] = fmaf(xv, sW[k * HID + j], hr[j]);
    }
    float a1 = 0.f, a2 = 0.f;
#pragma unroll
    for (int j = 0; j < HID; ++j) { a1 = fmaf(hr[j], sa[j], a1); a2 = fmaf(hr[j], sd[j], a2); }
    uint4* hp = (uint4*)(hb + (i << 3));
    uint4 w0, w1;
    w0.x = pack2(hr[0], hr[1]);   w0.y = pack2(hr[2], hr[3]);
    w0.z = pack2(hr[4], hr[5]);   w0.w = pack2(hr[6], hr[7]);
    w1.x = pack2(hr[8], hr[9]);   w1.y = pack2(hr[10], hr[11]);
    w1.z = pack2(hr[12], hr[13]); w1.w = pack2(hr[14], hr[15]);
    hp[0] = w0; hp[1] = w1;
    as_[i] = a1; ad_[i] = a2;
}

// ---------------- GAT aggregation: lane-per-node, chunk-8 MLP, bf16 h gathers, bf16 t out ----
__global__ void __launch_bounds__(256, 4)
gat_agg(const int* __restrict__ rowStart, const int* __restrict__ csrSrc,
        const unsigned int* __restrict__ hb, const float* __restrict__ as_,
        const float* __restrict__ ad_, const float* __restrict__ prmL,
        const int* __restrict__ batch,
        unsigned int* __restrict__ tb, float* __restrict__ gsum,
        float* __restrict__ gsumsq, int N) {
    __shared__ float sv[256][HID + 1];
    __shared__ int sg[256];
    int tid = threadIdx.x;
    int node = blockIdx.x * 256 + tid;
    bool valid = node < N;
    float acc[HID];
    float tv[HID];
    int g = -1;
    if (valid) {
        int start = rowStart[node];
        int end = rowStart[node + 1];
        float adi = ad_[node];
        float zs = as_[node] + adi;
        float e_self = zs > 0.f ? zs : NEG_SLOPE * zs;
        float m = e_self, ssum = 0.f;
#pragma unroll
        for (int f = 0; f < HID; ++f) acc[f] = 0.f;
        for (int base = start; base < end; base += 8) {
            int rem = end - base;
            int s[8];
            s[0] = csrSrc[base];
#pragma unroll
            for (int k = 1; k < 8; ++k) s[k] = (k < rem) ? csrSrc[base + k] : s[0];
            float av[8];
#pragma unroll
            for (int k = 0; k < 8; ++k) av[k] = as_[s[k]];
            uint4 ra[8], rb[8];
#pragma unroll
            for (int k = 0; k < 8; ++k) {
                const uint4* hq = (const uint4*)(hb + (s[k] << 3));
                ra[k] = hq[0]; rb[k] = hq[1];
            }
            float e[8];
#pragma unroll
            for (int k = 0; k < 8; ++k) {
                float z = av[k] + adi;
                float ek = z > 0.f ? z : NEG_SLOPE * z;
                e[k] = (k < rem) ? ek : -1e30f;
            }
            float cm = e[0];
#pragma unroll
            for (int k = 1; k < 8; ++k) cm = fmaxf(cm, e[k]);
            if (cm > m) {
                float sc = __expf(m - cm);
                ssum *= sc;
#pragma unroll
                for (int f = 0; f < HID; ++f) acc[f] *= sc;
                m = cm;
            }
            float psum = 0.f;
#pragma unroll
            for (int k = 0; k < 8; ++k) {
                float p = __expf(e[k] - m);   // underflows to 0 for padded slots
                psum += p;
                fma_row(ra[k], rb[k], p, acc);
            }
            ssum += psum;
        }
        const uint4* hs = (const uint4*)(hb + (node << 3));
        uint4 rs0 = hs[0], rs1 = hs[1];
        float pself = __expf(e_self - m);
        ssum += pself;
        fma_row(rs0, rs1, pself, acc);
        float inv = 1.f / ssum;
#pragma unroll
        for (int f = 0; f < HID; ++f) tv[f] = fmaf(acc[f], inv, prmL[288 + f]);
        uint4* tp = (uint4*)(tb + (node << 3));
        uint4 w0, w1;
        w0.x = pack2(tv[0], tv[1]);   w0.y = pack2(tv[2], tv[3]);
        w0.z = pack2(tv[4], tv[5]);   w0.w = pack2(tv[6], tv[7]);
        w1.x = pack2(tv[8], tv[9]);   w1.y = pack2(tv[10], tv[11]);
        w1.z = pack2(tv[12], tv[13]); w1.w = pack2(tv[14], tv[15]);
        tp[0] = w0; tp[1] = w1;
        g = batch[node];
    }
    sg[tid] = valid ? g : -1;
#pragma unroll
    for (int f = 0; f < HID; ++f) sv[tid][f] = valid ? tv[f] : 0.f;
    __syncthreads();
    if (tid < 64) {
        int f = tid & 15;
        int seg = tid >> 4;
        int n0 = seg * 64, n1 = n0 + 64;
        float s1 = 0.f, s2 = 0.f;
        int cur = -2;
        for (int n = n0; n < n1; ++n) {
            int bg = sg[n];
            if (bg < 0) continue;
            if (bg != cur) {
                if (cur >= 0) { atomicAdd(&gsum[cur * HID + f], s1); atomicAdd(&gsumsq[cur * HID + f], s2); }
                cur = bg; s1 = 0.f; s2 = 0.f;
            }
            float v = sv[n][f];
            s1 += v; s2 += v * v;
        }
        if (cur >= 0) { atomicAdd(&gsum[cur * HID + f], s1); atomicAdd(&gsumsq[cur * HID + f], s2); }
    }
}

// ---------------- GraphNorm coefficients (self-zeroes stats for next layer) ----------------
__global__ void norm_coef(float* __restrict__ gsum, float* __restrict__ gsumsq,
                          const float* __restrict__ gcnt, const float* __restrict__ prmL,
                          float* __restrict__ A, float* __restrict__ B) {
    int idx = blockIdx.x * blockDim.x + threadIdx.x;
    if (idx < NGRAPH * HID) {
        int g = idx >> 4, f = idx & 15;
        float c = gcnt[g];
        float invc = c > 0.f ? 1.f / c : 0.f;
        float mean = gsum[idx] * invc;
        float msq = gsumsq[idx] * invc;
        gsum[idx] = 0.f; gsumsq[idx] = 0.f;   // ready for next layer's gat_agg
        float gaf = prmL[336 + f];
        float var = msq + (gaf * gaf - 2.f * gaf) * mean * mean;
        var = fmaxf(var, 0.f);
        float inv = rsqrtf(var + EPS_GN);
        float Af = prmL[304 + f] * inv;
        A[idx] = Af;
        B[idx] = prmL[320 + f] - Af * gaf * mean;
    }
}

// ---------------- fused norm+relu(+residual) + next-layer features / final pool ----------------
__global__ void norm_feat(const unsigned int* __restrict__ tb, const float* __restrict__ gA,
                          const float* __restrict__ gB, const int* __restrict__ batch,
                          float* __restrict__ xcur, int N, int residual, int isLast,
                          const float* __restrict__ prmNext,
                          unsigned int* __restrict__ hb, float* __restrict__ as_,
                          float* __restrict__ ad_, float* __restrict__ pooled) {
    __shared__ float sW[256], sa[HID], sd[HID];
    __shared__ float sv[256][HID + 1];
    __shared__ int sg[256];
    int tid = threadIdx.x;
    if (!isLast) {
        sW[tid] = prmNext[tid];
        if (tid < HID) { sa[tid] = prmNext[256 + tid]; sd[tid] = prmNext[272 + tid]; }
        __syncthreads();
    }
    int i = blockIdx.x * 256 + tid;
    float v[HID];
    int g = -1;
    if (i < N) {
        g = batch[i];
        const float* Ar = gA + g * HID;
        const float* Br = gB + g * HID;
        const uint4* tp = (const uint4*)(tb + (i << 3));
        uint4 u0 = tp[0], u1 = tp[1];
        unsigned int us[8] = {u0.x, u0.y, u0.z, u0.w, u1.x, u1.y, u1.z, u1.w};
        float ts[HID];
#pragma unroll
        for (int q = 0; q < 8; ++q) {
            ts[2 * q]     = __uint_as_float(us[q] << 16);
            ts[2 * q + 1] = __uint_as_float(us[q] & 0xFFFF0000u);
        }
        float xs[HID];
        if (residual) {
            const float4* xp = (const float4*)(xcur + (i << 4));
#pragma unroll
            for (int q = 0; q < 4; ++q) {
                float4 x4 = xp[q];
                xs[q*4+0] = x4.x; xs[q*4+1] = x4.y; xs[q*4+2] = x4.z; xs[q*4+3] = x4.w;
            }
        } else {
#pragma unroll
            for (int f = 0; f < HID; ++f) xs[f] = 0.f;
        }
#pragma unroll
        for (int f = 0; f < HID; ++f) {
            float val = fmaf(Ar[f], ts[f], Br[f]) + xs[f];
            v[f] = fmaxf(val, 0.f);
        }
    }
    if (isLast) {
        sg[tid] = (i < N) ? g : -1;
#pragma unroll
        for (int f = 0; f < HID; ++f) sv[tid][f] = (i < N) ? v[f] : 0.f;
        __syncthreads();
        if (tid < 64) {
            int f = tid & 15;
            int seg = tid >> 4;
            int n0 = seg * 64, n1 = n0 + 64;
            float s1 = 0.f;
            int cur = -2;
            for (int n = n0; n < n1; ++n) {
                int bg = sg[n];
                if (bg < 0) continue;
                if (bg != cur) { if (cur >= 0) atomicAdd(&pooled[cur * HID + f], s1); cur = bg; s1 = 0.f; }
                s1 += sv[n][f];
            }
            if (cur >= 0) atomicAdd(&pooled[cur * HID + f], s1);
        }
    } else if (i < N) {
        float4* xp = (float4*)(xcur + (i << 4));
#pragma unroll
        for (int q = 0; q < 4; ++q) xp[q] = make_float4(v[q*4+0], v[q*4+1], v[q*4+2], v[q*4+3]);
        float hr[HID];
#pragma unroll
        for (int j = 0; j < HID; ++j) hr[j] = 0.f;
#pragma unroll
        for (int k = 0; k < HID; ++k) {
            float xv = v[k];
#pragma unroll
            for (int j = 0; j < HID; ++j) hr[j] = fmaf(xv, sW[k * HID + j], hr[j]);
        }
        float a1 = 0.f, a2 = 0.f;
#pragma unroll
        for (int j = 0; j < HID; ++j) { a1 = fmaf(hr[j], sa[j], a1); a2 = fmaf(hr[j], sd[j], a2); }
        uint4* hp = (uint4*)(hb + (i << 3));
        uint4 w0, w1;
        w0.x = pack2(hr[0], hr[1]);   w0.y = pack2(hr[2], hr[3]);
        w0.z = pack2(hr[4], hr[5]);   w0.w = pack2(hr[6], hr[7]);
        w1.x = pack2(hr[8], hr[9]);   w1.y = pack2(hr[10], hr[11]);
        w1.z = pack2(hr[12], hr[13]); w1.w = pack2(hr[14], hr[15]);
        hp[0] = w0; hp[1] = w1;
        as_[i] = a1; ad_[i] = a2;
    }
}

// ---------------- final linear ----------------
__global__ void final_lin(const float* __restrict__ pooled, const float* __restrict__ gcnt,
                          const float* __restrict__ prm, const int* __restrict__ flags,
                          void* __restrict__ out) {
    int g = blockIdx.x * blockDim.x + threadIdx.x;
    if (g < NGRAPH) {
        float c = gcnt[g];
        float invc = c > 0.f ? 1.f / c : 0.f;
        float o0 = prm[1440], o1 = prm[1441];
#pragma unroll
        for (int f = 0; f < HID; ++f) {
            float p = pooled[g * HID + f] * invc;
            o0 = fmaf(p, prm[1408 + f * 2 + 0], o0);
            o1 = fmaf(p, prm[1408 + f * 2 + 1], o1);
        }
        if (flags[0]) {
            ((bf16*)out)[g * 2 + 0] = __float2bfloat16(o0);
            ((bf16*)out)[g * 2 + 1] = __float2bfloat16(o1);
        } else {
            ((float*)out)[g * 2 + 0] = o0;
            ((float*)out)[g * 2 + 1] = o1;
        }
    }
}

extern "C" void kernel_launch(void* const* d_in, const int* in_sizes, int n_in,
                              void* d_out, int out_size, void* d_ws, size_t ws_size,
                              hipStream_t stream) {
    const void* x = d_in[0];
    const int* ei = (const int*)d_in[1];
    const int* batch = (const int*)d_in[2];
    int N = in_sizes[2];
    int E = in_sizes[1] / 2;
    int din0 = in_sizes[0] / N;
    int NB = (N + BS - 1) / BS;

    float* ws = (float*)d_ws;
    int* flags = (int*)ws;                          // 16 ints
    float* prm = ws + 16;                           // 2048 floats
    unsigned int* hb = (unsigned int*)(ws + 4096);  // N*8 u32 (bf16-packed h)
    unsigned int* tb = hb + (size_t)N * 8;          // N*8 u32 (bf16-packed t)
    float* xcur = (float*)(tb + (size_t)N * 8);     // N*16
    float* as_ = xcur + (size_t)N * HID;            // N
    float* ad_ = as_ + N;                           // N
    int* rowStart = (int*)(ad_ + N);                // N+1
    int* bcnt = rowStart + (N + 1);                 // NBMAX
    int* gBase = bcnt + NBMAX;                      // NBMAX+1
    int* gCursor = gBase + NBMAX + 1;               // NBMAX
    int* csrSrc = gCursor + NBMAX;                  // E (+pad)
    float* gsum = (float*)(csrSrc + E + 64);        // G*16
    float* gsumsq = gsum + NGRAPH * HID;
    float* gA = gsumsq + NGRAPH * HID;
    float* gB = gA + NGRAPH * HID;
    float* pooled = gB + NGRAPH * HID;
    float* gcnt = pooled + NGRAPH * HID;
    uint2* binned = (uint2*)tb;   // E*8B, aliases tb+xcur (48MB >= 40MB); dead before layer 0

    PtrPack pk;
    int n = 0;
    for (int l = 0; l < 4; ++l) {
        int dl = (l == 0) ? din0 : HID;
        int base = l * 352;
        const int offs[7] = {0, 256, 272, 288, 304, 320, 336};
        const int cnts[7] = {dl * HID, HID, HID, HID, HID, HID, HID};
        for (int j = 0; j < 7; ++j) {
            pk.src[n] = d_in[4 + l * 7 + j];
            pk.cnt[n] = cnts[j];
            pk.dstoff[n] = base + offs[j];
            ++n;
        }
    }
    pk.src[n] = d_in[32]; pk.cnt[n] = HID * 2; pk.dstoff[n] = 1408; ++n;
    pk.src[n] = d_in[33]; pk.cnt[n] = 2;       pk.dstoff[n] = 1440; ++n;
    pk.n = n;

    int nbN = (N + 255) / 256;

    detect_cvt<<<1, 256, 0, stream>>>(x, ei, flags, pk, prm);

    hipMemsetAsync(bcnt, 0, NBMAX * sizeof(int), stream);
    hipMemsetAsync(pooled, 0, NGRAPH * HID * sizeof(float), stream);
    hipMemsetAsync(gsum, 0, 2 * NGRAPH * HID * sizeof(float), stream);  // first layer only; norm_coef re-zeroes

    bucket_count<<<1024, 256, 0, stream>>>(ei, E, flags, bcnt, NB);
    scan_buckets<<<1, 256, 0, stream>>>(bcnt, NB, E, gBase, gCursor, rowStart, N);
    bucket_scatter<<<1024, 256, 0, stream>>>(ei, E, flags, gCursor, binned, NB);
    bucket_sort<<<NB, 1024, 0, stream>>>(binned, gBase, csrSrc, rowStart, N);
    graph_cnt_k<<<(NGRAPH + 255) / 256, 256, 0, stream>>>(batch, N, gcnt);

    node_feat0<<<nbN, 256, 0, stream>>>(x, din0, flags, prm, hb, as_, ad_, N);

    for (int l = 0; l < 4; ++l) {
        const float* prmL = prm + l * 352;
        const float* prmNext = prm + (l + 1 < 4 ? (l + 1) * 352 : 0);

        gat_agg<<<nbN, 256, 0, stream>>>(rowStart, csrSrc, hb, as_, ad_, prmL, batch,
                                         tb, gsum, gsumsq, N);
        norm_coef<<<(NGRAPH * HID + 255) / 256, 256, 0, stream>>>(gsum, gsumsq, gcnt, prmL, gA, gB);
        norm_feat<<<nbN, 256, 0, stream>>>(tb, gA, gB, batch, xcur, N, l > 0 ? 1 : 0,
                                           l == 3 ? 1 : 0, prmNext, hb, as_, ad_, pooled);
    }

    final_lin<<<(NGRAPH + 255) / 256, 256, 0, stream>>>(pooled, gcnt, prm, flags, d_out);
}

// Round 8
// 1029.907 us; speedup vs baseline: 1.3540x; 1.3540x over previous
//
#include <hip/hip_runtime.h>
#include <hip/hip_bf16.h>

#define HID 16
#define NGRAPH 1000
#define NEG_SLOPE 0.2f
#define EPS_GN 1e-5f
#define BSH 11              // bucket shift: 2048 dsts per bucket
#define BS 2048             // bucket span (power of 2)
#define NBMAX 2048
#define CHK 4096            // edges per scatter chunk

typedef __hip_bfloat16 bf16;

static __device__ __forceinline__ float b2f(bf16 v) { return __bfloat162float(v); }

// pack two floats into one u32 holding two RNE-rounded bf16s (a=low, b=high)
static __device__ __forceinline__ unsigned int pack2(float a, float b) {
    unsigned int ia = __float_as_uint(a);
    unsigned int ib = __float_as_uint(b);
    ia += 0x7FFFu + ((ia >> 16) & 1u);
    ib += 0x7FFFu + ((ib >> 16) & 1u);
    return (ia >> 16) | (ib & 0xFFFF0000u);
}

// acc[0..15] += p * bf16row(ra,rb)
static __device__ __forceinline__ void fma_row(const uint4 ra, const uint4 rb, float p,
                                               float* __restrict__ acc) {
    unsigned int us[8] = {ra.x, ra.y, ra.z, ra.w, rb.x, rb.y, rb.z, rb.w};
#pragma unroll
    for (int q = 0; q < 8; ++q) {
        float lo = __uint_as_float(us[q] << 16);
        float hi = __uint_as_float(us[q] & 0xFFFF0000u);
        acc[2 * q]     = fmaf(p, lo, acc[2 * q]);
        acc[2 * q + 1] = fmaf(p, hi, acc[2 * q + 1]);
    }
}

struct PtrPack { const void* src[30]; int cnt[30]; int dstoff[30]; int n; };

// ---------------- dtype detection + param conversion (single block) ----------------
__global__ void detect_cvt(const void* x, const void* ei, int* flags, PtrPack pk,
                           float* __restrict__ dst) {
    __shared__ int cbf, czero;
    __shared__ int isbS;
    int t = threadIdx.x;
    if (t == 0) { cbf = 0; czero = 0; }
    __syncthreads();
    const unsigned int* xw = (const unsigned int*)x;
    unsigned int w = xw[t * 4];
    int e_lo = (int)((w >> 7) & 0xFF);
    if (e_lo >= 100 && e_lo <= 140) atomicAdd(&cbf, 1);
    const unsigned int* ew = (const unsigned int*)ei;
    if (ew[2 * t + 1] == 0u) atomicAdd(&czero, 1);
    __syncthreads();
    if (t == 0) {
        int isb = (cbf >= 192) ? 1 : 0;
        flags[0] = isb;
        flags[1] = (czero >= 250) ? 1 : 0;
        isbS = isb;
    }
    __syncthreads();
    int isb = isbS;
    for (int j = 0; j < pk.n; ++j) {
        const void* s = pk.src[j];
        int c = pk.cnt[j], o = pk.dstoff[j];
        for (int i = t; i < c; i += blockDim.x) {
            float v = isb ? b2f(((const bf16*)s)[i]) : ((const float*)s)[i];
            dst[o + i] = v;
        }
    }
}

static __device__ __forceinline__ int ld_src(const int* ei, int E, int e, int i64) {
    return i64 ? ei[2ll * e] : ei[e];
}
static __device__ __forceinline__ int ld_dst(const int* ei, int E, int e, int i64) {
    return i64 ? ei[2ll * (E + e)] : ei[(long long)E + e];
}

// ---------------- CSR build: two-level bucket counting sort ----------------

__global__ void bucket_count(const int* __restrict__ ei, int E, const int* __restrict__ flags,
                             int* __restrict__ bcnt, int NB) {
    __shared__ int lh[NBMAX];
    int tid = threadIdx.x;
    for (int i = tid; i < NB; i += 256) lh[i] = 0;
    __syncthreads();
    int i64 = flags[1];
    int stride = gridDim.x * 256;
    for (int e = blockIdx.x * 256 + tid; e < E; e += stride)
        atomicAdd(&lh[ld_dst(ei, E, e, i64) >> BSH], 1);
    __syncthreads();
    for (int i = tid; i < NB; i += 256)
        if (lh[i]) atomicAdd(&bcnt[i], lh[i]);
}

__global__ void scan_buckets(const int* __restrict__ bcnt, int NB, int E,
                             int* __restrict__ gBase, int* __restrict__ gCursor,
                             int* __restrict__ rowStart, int N) {
    __shared__ int part[256];
    int t = threadIdx.x;
    int per = (NB + 255) >> 8;
    int lo = t * per, hi = min(lo + per, NB);
    int s = 0;
    for (int i = lo; i < hi; ++i) s += bcnt[i];
    part[t] = s;
    __syncthreads();
    for (int off = 1; off < 256; off <<= 1) {
        int v = (t >= off) ? part[t - off] : 0;
        __syncthreads();
        part[t] += v;
        __syncthreads();
    }
    int acc = (t == 0) ? 0 : part[t - 1];
    for (int i = lo; i < hi; ++i) {
        gBase[i] = acc; gCursor[i] = acc;
        acc += bcnt[i];
    }
    if (t == 0) { gBase[NB] = E; rowStart[N] = E; }
}

__global__ void bucket_scatter(const int* __restrict__ ei, int E, const int* __restrict__ flags,
                               int* __restrict__ gCursor, uint2* __restrict__ binned, int NB) {
    __shared__ int lh[NBMAX];
    __shared__ int lbase[NBMAX];
    __shared__ int lcur[NBMAX];
    int tid = threadIdx.x;
    int i64 = flags[1];
    int nchunk = (E + CHK - 1) / CHK;
    for (int chunk = blockIdx.x; chunk < nchunk; chunk += gridDim.x) {
        int c0 = chunk * CHK;
        int c1 = min(c0 + CHK, E);
        for (int i = tid; i < NB; i += 256) lh[i] = 0;
        __syncthreads();
        for (int e = c0 + tid; e < c1; e += 256)
            atomicAdd(&lh[ld_dst(ei, E, e, i64) >> BSH], 1);
        __syncthreads();
        for (int b = tid; b < NB; b += 256) {
            int c = lh[b];
            lbase[b] = c ? atomicAdd(&gCursor[b], c) : 0;
            lcur[b] = 0;
        }
        __syncthreads();
        for (int e = c0 + tid; e < c1; e += 256) {
            int d = ld_dst(ei, E, e, i64);
            int s = ld_src(ei, E, e, i64);
            int b = d >> BSH;
            int off = atomicAdd(&lcur[b], 1);
            binned[lbase[b] + off] = make_uint2((unsigned)s, (unsigned)(d & (BS - 1)));
        }
        __syncthreads();
    }
}

__global__ void bucket_sort(const uint2* __restrict__ binned, const int* __restrict__ gBase,
                            int* __restrict__ csrSrc, int* __restrict__ rowStart, int N) {
    __shared__ int hist[BS];
    __shared__ int tsum[1024];
    int tid = threadIdx.x;
    int b = blockIdx.x;
    int base = gBase[b];
    int cnt = gBase[b + 1] - base;
    for (int i = tid; i < BS; i += 1024) hist[i] = 0;
    __syncthreads();
    for (int i = tid; i < cnt; i += 1024)
        atomicAdd(&hist[binned[base + i].y], 1);
    __syncthreads();
    int a0 = hist[2 * tid], a1 = hist[2 * tid + 1];
    tsum[tid] = a0 + a1;
    __syncthreads();
    for (int off = 1; off < 1024; off <<= 1) {
        int v = (tid >= off) ? tsum[tid - off] : 0;
        __syncthreads();
        tsum[tid] += v;
        __syncthreads();
    }
    int excl = (tid == 0) ? 0 : tsum[tid - 1];
    int d0 = b * BS + 2 * tid;
    if (d0 < N) rowStart[d0] = base + excl;
    if (d0 + 1 < N) rowStart[d0 + 1] = base + excl + a0;
    __syncthreads();
    hist[2 * tid] = excl;
    hist[2 * tid + 1] = excl + a0;
    __syncthreads();
    for (int i = tid; i < cnt; i += 1024) {
        uint2 pr = binned[base + i];
        int off = atomicAdd(&hist[pr.y], 1);
        csrSrc[base + off] = (int)pr.x;
    }
}

__global__ void graph_cnt_k(const int* __restrict__ batch, int N, float* __restrict__ gcnt) {
    int g = blockIdx.x * blockDim.x + threadIdx.x;
    if (g < NGRAPH) {
        int lo = 0, hi = N;
        while (lo < hi) { int mid = (lo + hi) >> 1; if (batch[mid] < g) lo = mid + 1; else hi = mid; }
        int lb = lo;
        lo = 0; hi = N;
        while (lo < hi) { int mid = (lo + hi) >> 1; if (batch[mid] <= g) lo = mid + 1; else hi = mid; }
        gcnt[g] = (float)(lo - lb);
    }
}

// ---------------- layer-0 node transform (writes bf16-packed h) ----------------
__global__ void node_feat0(const void* __restrict__ xin, int din,
                           const int* __restrict__ flags, const float* __restrict__ prmL,
                           unsigned int* __restrict__ hb, float* __restrict__ as_,
                           float* __restrict__ ad_, int N) {
    __shared__ float sW[256], sa[HID], sd[HID];
    int t = threadIdx.x;
    if (t < din * HID) sW[t] = prmL[t];
    if (t < HID) { sa[t] = prmL[256 + t]; sd[t] = prmL[272 + t]; }
    __syncthreads();
    int i = blockIdx.x * blockDim.x + t;
    if (i >= N) return;
    int isb = flags[0];
    const float* xf = (const float*)xin;
    const bf16* xb = (const bf16*)xin;
    float hr[HID];
#pragma unroll
    for (int j = 0; j < HID; ++j) hr[j] = 0.f;
    int base = i * din;
    for (int k = 0; k < din; ++k) {
        float xv = isb ? b2f(xb[base + k]) : xf[base + k];
#pragma unroll
        for (int j = 0; j < HID; ++j) hr[j] = fmaf(xv, sW[k * HID + j], hr[j]);
    }
    float a1 = 0.f, a2 = 0.f;
#pragma unroll
    for (int j = 0; j < HID; ++j) { a1 = fmaf(hr[j], sa[j], a1); a2 = fmaf(hr[j], sd[j], a2); }
    uint4* hp = (uint4*)(hb + (i << 3));
    uint4 w0, w1;
    w0.x = pack2(hr[0], hr[1]);   w0.y = pack2(hr[2], hr[3]);
    w0.z = pack2(hr[4], hr[5]);   w0.w = pack2(hr[6], hr[7]);
    w1.x = pack2(hr[8], hr[9]);   w1.y = pack2(hr[10], hr[11]);
    w1.z = pack2(hr[12], hr[13]); w1.w = pack2(hr[14], hr[15]);
    hp[0] = w0; hp[1] = w1;
    as_[i] = a1; ad_[i] = a2;
}

// ---------------- GAT aggregation: lane-per-node, chunk-4 + index prefetch, bf16 h/t ----------
// chunk-4 chosen deliberately: chunk-8 spills (VGPR>128 -> scratch, r7: +213MB WRITE, 1.7x slower)
__global__ void __launch_bounds__(256, 4)
gat_agg(const int* __restrict__ rowStart, const int* __restrict__ csrSrc,
        const unsigned int* __restrict__ hb, const float* __restrict__ as_,
        const float* __restrict__ ad_, const float* __restrict__ prmL,
        const int* __restrict__ batch,
        unsigned int* __restrict__ tb, float* __restrict__ gsum,
        float* __restrict__ gsumsq, int N) {
    __shared__ float sv[256][HID + 1];
    __shared__ int sg[256];
    int tid = threadIdx.x;
    int node = blockIdx.x * 256 + tid;
    bool valid = node < N;
    float acc[HID];
    float tv[HID];
    int g = -1;
    if (valid) {
        int start = rowStart[node];
        int end = rowStart[node + 1];
        float adi = ad_[node];
        float zs = as_[node] + adi;
        float e_self = zs > 0.f ? zs : NEG_SLOPE * zs;
        float m = e_self, ssum = 0.f;
#pragma unroll
        for (int f = 0; f < HID; ++f) acc[f] = 0.f;
        int s[4];
        if (start < end) {
            int rem = end - start;
            s[0] = csrSrc[start];
#pragma unroll
            for (int k = 1; k < 4; ++k) s[k] = (k < rem) ? csrSrc[start + k] : s[0];
        }
        for (int base = start; base < end; base += 4) {
            int rem = end - base;
            // gathers for current chunk (indices already in regs)
            float a0 = as_[s[0]], a1 = as_[s[1]], a2 = as_[s[2]], a3 = as_[s[3]];
            const uint4* h0 = (const uint4*)(hb + (s[0] << 3));
            const uint4* h1 = (const uint4*)(hb + (s[1] << 3));
            const uint4* h2 = (const uint4*)(hb + (s[2] << 3));
            const uint4* h3 = (const uint4*)(hb + (s[3] << 3));
            uint4 r00 = h0[0], r01 = h0[1];
            uint4 r10 = h1[0], r11 = h1[1];
            uint4 r20 = h2[0], r21 = h2[1];
            uint4 r30 = h3[0], r31 = h3[1];
            // prefetch next chunk's indices while gathers are in flight
            int nbase = base + 4;
            if (nbase < end) {
                int nrem = end - nbase;
                int sn0 = csrSrc[nbase];
                s[0] = sn0;
#pragma unroll
                for (int k = 1; k < 4; ++k) s[k] = (k < nrem) ? csrSrc[nbase + k] : sn0;
            }
            float z0 = a0 + adi, z1 = a1 + adi, z2 = a2 + adi, z3 = a3 + adi;
            float e0 = z0 > 0.f ? z0 : NEG_SLOPE * z0;
            float e1 = (1 < rem) ? (z1 > 0.f ? z1 : NEG_SLOPE * z1) : -1e30f;
            float e2 = (2 < rem) ? (z2 > 0.f ? z2 : NEG_SLOPE * z2) : -1e30f;
            float e3 = (3 < rem) ? (z3 > 0.f ? z3 : NEG_SLOPE * z3) : -1e30f;
            float cm = fmaxf(fmaxf(e0, e1), fmaxf(e2, e3));
            if (cm > m) {
                float sc = __expf(m - cm);
                ssum *= sc;
#pragma unroll
                for (int f = 0; f < HID; ++f) acc[f] *= sc;
                m = cm;
            }
            float p0 = __expf(e0 - m);
            float p1 = __expf(e1 - m);
            float p2 = __expf(e2 - m);
            float p3 = __expf(e3 - m);
            ssum += p0 + p1 + p2 + p3;
            fma_row(r00, r01, p0, acc);
            fma_row(r10, r11, p1, acc);
            fma_row(r20, r21, p2, acc);
            fma_row(r30, r31, p3, acc);
        }
        const uint4* hs = (const uint4*)(hb + (node << 3));
        uint4 rs0 = hs[0], rs1 = hs[1];
        float pself = __expf(e_self - m);
        ssum += pself;
        fma_row(rs0, rs1, pself, acc);
        float inv = 1.f / ssum;
#pragma unroll
        for (int f = 0; f < HID; ++f) tv[f] = fmaf(acc[f], inv, prmL[288 + f]);
        uint4* tp = (uint4*)(tb + (node << 3));
        uint4 w0, w1;
        w0.x = pack2(tv[0], tv[1]);   w0.y = pack2(tv[2], tv[3]);
        w0.z = pack2(tv[4], tv[5]);   w0.w = pack2(tv[6], tv[7]);
        w1.x = pack2(tv[8], tv[9]);   w1.y = pack2(tv[10], tv[11]);
        w1.z = pack2(tv[12], tv[13]); w1.w = pack2(tv[14], tv[15]);
        tp[0] = w0; tp[1] = w1;
        g = batch[node];
    }
    sg[tid] = valid ? g : -1;
#pragma unroll
    for (int f = 0; f < HID; ++f) sv[tid][f] = valid ? tv[f] : 0.f;
    __syncthreads();
    if (tid < 64) {
        int f = tid & 15;
        int seg = tid >> 4;
        int n0 = seg * 64, n1 = n0 + 64;
        float s1 = 0.f, s2 = 0.f;
        int cur = -2;
        for (int n = n0; n < n1; ++n) {
            int bg = sg[n];
            if (bg < 0) continue;
            if (bg != cur) {
                if (cur >= 0) { atomicAdd(&gsum[cur * HID + f], s1); atomicAdd(&gsumsq[cur * HID + f], s2); }
                cur = bg; s1 = 0.f; s2 = 0.f;
            }
            float v = sv[n][f];
            s1 += v; s2 += v * v;
        }
        if (cur >= 0) { atomicAdd(&gsum[cur * HID + f], s1); atomicAdd(&gsumsq[cur * HID + f], s2); }
    }
}

// ---------------- GraphNorm coefficients (self-zeroes stats for next layer) ----------------
__global__ void norm_coef(float* __restrict__ gsum, float* __restrict__ gsumsq,
                          const float* __restrict__ gcnt, const float* __restrict__ prmL,
                          float* __restrict__ A, float* __restrict__ B) {
    int idx = blockIdx.x * blockDim.x + threadIdx.x;
    if (idx < NGRAPH * HID) {
        int g = idx >> 4, f = idx & 15;
        float c = gcnt[g];
        float invc = c > 0.f ? 1.f / c : 0.f;
        float mean = gsum[idx] * invc;
        float msq = gsumsq[idx] * invc;
        gsum[idx] = 0.f; gsumsq[idx] = 0.f;   // ready for next layer's gat_agg
        float gaf = prmL[336 + f];
        float var = msq + (gaf * gaf - 2.f * gaf) * mean * mean;
        var = fmaxf(var, 0.f);
        float inv = rsqrtf(var + EPS_GN);
        float Af = prmL[304 + f] * inv;
        A[idx] = Af;
        B[idx] = prmL[320 + f] - Af * gaf * mean;
    }
}

// ---------------- fused norm+relu(+residual) + next-layer features / final pool ----------------
__global__ void norm_feat(const unsigned int* __restrict__ tb, const float* __restrict__ gA,
                          const float* __restrict__ gB, const int* __restrict__ batch,
                          float* __restrict__ xcur, int N, int residual, int isLast,
                          const float* __restrict__ prmNext,
                          unsigned int* __restrict__ hb, float* __restrict__ as_,
                          float* __restrict__ ad_, float* __restrict__ pooled) {
    __shared__ float sW[256], sa[HID], sd[HID];
    __shared__ float sv[256][HID + 1];
    __shared__ int sg[256];
    int tid = threadIdx.x;
    if (!isLast) {
        sW[tid] = prmNext[tid];
        if (tid < HID) { sa[tid] = prmNext[256 + tid]; sd[tid] = prmNext[272 + tid]; }
        __syncthreads();
    }
    int i = blockIdx.x * 256 + tid;
    float v[HID];
    int g = -1;
    if (i < N) {
        g = batch[i];
        const float* Ar = gA + g * HID;
        const float* Br = gB + g * HID;
        const uint4* tp = (const uint4*)(tb + (i << 3));
        uint4 u0 = tp[0], u1 = tp[1];
        unsigned int us[8] = {u0.x, u0.y, u0.z, u0.w, u1.x, u1.y, u1.z, u1.w};
        float ts[HID];
#pragma unroll
        for (int q = 0; q < 8; ++q) {
            ts[2 * q]     = __uint_as_float(us[q] << 16);
            ts[2 * q + 1] = __uint_as_float(us[q] & 0xFFFF0000u);
        }
        float xs[HID];
        if (residual) {
            const float4* xp = (const float4*)(xcur + (i << 4));
#pragma unroll
            for (int q = 0; q < 4; ++q) {
                float4 x4 = xp[q];
                xs[q*4+0] = x4.x; xs[q*4+1] = x4.y; xs[q*4+2] = x4.z; xs[q*4+3] = x4.w;
            }
        } else {
#pragma unroll
            for (int f = 0; f < HID; ++f) xs[f] = 0.f;
        }
#pragma unroll
        for (int f = 0; f < HID; ++f) {
            float val = fmaf(Ar[f], ts[f], Br[f]) + xs[f];
            v[f] = fmaxf(val, 0.f);
        }
    }
    if (isLast) {
        sg[tid] = (i < N) ? g : -1;
#pragma unroll
        for (int f = 0; f < HID; ++f) sv[tid][f] = (i < N) ? v[f] : 0.f;
        __syncthreads();
        if (tid < 64) {
            int f = tid & 15;
            int seg = tid >> 4;
            int n0 = seg * 64, n1 = n0 + 64;
            float s1 = 0.f;
            int cur = -2;
            for (int n = n0; n < n1; ++n) {
                int bg = sg[n];
                if (bg < 0) continue;
                if (bg != cur) { if (cur >= 0) atomicAdd(&pooled[cur * HID + f], s1); cur = bg; s1 = 0.f; }
                s1 += sv[n][f];
            }
            if (cur >= 0) atomicAdd(&pooled[cur * HID + f], s1);
        }
    } else if (i < N) {
        float4* xp = (float4*)(xcur + (i << 4));
#pragma unroll
        for (int q = 0; q < 4; ++q) xp[q] = make_float4(v[q*4+0], v[q*4+1], v[q*4+2], v[q*4+3]);
        float hr[HID];
#pragma unroll
        for (int j = 0; j < HID; ++j) hr[j] = 0.f;
#pragma unroll
        for (int k = 0; k < HID; ++k) {
            float xv = v[k];
#pragma unroll
            for (int j = 0; j < HID; ++j) hr[j] = fmaf(xv, sW[k * HID + j], hr[j]);
        }
        float a1 = 0.f, a2 = 0.f;
#pragma unroll
        for (int j = 0; j < HID; ++j) { a1 = fmaf(hr[j], sa[j], a1); a2 = fmaf(hr[j], sd[j], a2); }
        uint4* hp = (uint4*)(hb + (i << 3));
        uint4 w0, w1;
        w0.x = pack2(hr[0], hr[1]);   w0.y = pack2(hr[2], hr[3]);
        w0.z = pack2(hr[4], hr[5]);   w0.w = pack2(hr[6], hr[7]);
        w1.x = pack2(hr[8], hr[9]);   w1.y = pack2(hr[10], hr[11]);
        w1.z = pack2(hr[12], hr[13]); w1.w = pack2(hr[14], hr[15]);
        hp[0] = w0; hp[1] = w1;
        as_[i] = a1; ad_[i] = a2;
    }
}

// ---------------- final linear ----------------
__global__ void final_lin(const float* __restrict__ pooled, const float* __restrict__ gcnt,
                          const float* __restrict__ prm, const int* __restrict__ flags,
                          void* __restrict__ out) {
    int g = blockIdx.x * blockDim.x + threadIdx.x;
    if (g < NGRAPH) {
        float c = gcnt[g];
        float invc = c > 0.f ? 1.f / c : 0.f;
        float o0 = prm[1440], o1 = prm[1441];
#pragma unroll
        for (int f = 0; f < HID; ++f) {
            float p = pooled[g * HID + f] * invc;
            o0 = fmaf(p, prm[1408 + f * 2 + 0], o0);
            o1 = fmaf(p, prm[1408 + f * 2 + 1], o1);
        }
        if (flags[0]) {
            ((bf16*)out)[g * 2 + 0] = __float2bfloat16(o0);
            ((bf16*)out)[g * 2 + 1] = __float2bfloat16(o1);
        } else {
            ((float*)out)[g * 2 + 0] = o0;
            ((float*)out)[g * 2 + 1] = o1;
        }
    }
}

extern "C" void kernel_launch(void* const* d_in, const int* in_sizes, int n_in,
                              void* d_out, int out_size, void* d_ws, size_t ws_size,
                              hipStream_t stream) {
    const void* x = d_in[0];
    const int* ei = (const int*)d_in[1];
    const int* batch = (const int*)d_in[2];
    int N = in_sizes[2];
    int E = in_sizes[1] / 2;
    int din0 = in_sizes[0] / N;
    int NB = (N + BS - 1) / BS;

    float* ws = (float*)d_ws;
    int* flags = (int*)ws;                          // 16 ints
    float* prm = ws + 16;                           // 2048 floats
    unsigned int* hb = (unsigned int*)(ws + 4096);  // N*8 u32 (bf16-packed h)
    unsigned int* tb = hb + (size_t)N * 8;          // N*8 u32 (bf16-packed t)
    float* xcur = (float*)(tb + (size_t)N * 8);     // N*16
    float* as_ = xcur + (size_t)N * HID;            // N
    float* ad_ = as_ + N;                           // N
    int* rowStart = (int*)(ad_ + N);                // N+1
    int* bcnt = rowStart + (N + 1);                 // NBMAX
    int* gBase = bcnt + NBMAX;                      // NBMAX+1
    int* gCursor = gBase + NBMAX + 1;               // NBMAX
    int* csrSrc = gCursor + NBMAX;                  // E (+pad)
    float* gsum = (float*)(csrSrc + E + 64);        // G*16
    float* gsumsq = gsum + NGRAPH * HID;
    float* gA = gsumsq + NGRAPH * HID;
    float* gB = gA + NGRAPH * HID;
    float* pooled = gB + NGRAPH * HID;
    float* gcnt = pooled + NGRAPH * HID;
    uint2* binned = (uint2*)tb;   // E*8B, aliases tb+xcur; dead before layer 0

    PtrPack pk;
    int n = 0;
    for (int l = 0; l < 4; ++l) {
        int dl = (l == 0) ? din0 : HID;
        int base = l * 352;
        const int offs[7] = {0, 256, 272, 288, 304, 320, 336};
        const int cnts[7] = {dl * HID, HID, HID, HID, HID, HID, HID};
        for (int j = 0; j < 7; ++j) {
            pk.src[n] = d_in[4 + l * 7 + j];
            pk.cnt[n] = cnts[j];
            pk.dstoff[n] = base + offs[j];
            ++n;
        }
    }
    pk.src[n] = d_in[32]; pk.cnt[n] = HID * 2; pk.dstoff[n] = 1408; ++n;
    pk.src[n] = d_in[33]; pk.cnt[n] = 2;       pk.dstoff[n] = 1440; ++n;
    pk.n = n;

    int nbN = (N + 255) / 256;

    detect_cvt<<<1, 256, 0, stream>>>(x, ei, flags, pk, prm);

    hipMemsetAsync(bcnt, 0, NBMAX * sizeof(int), stream);
    hipMemsetAsync(pooled, 0, NGRAPH * HID * sizeof(float), stream);
    hipMemsetAsync(gsum, 0, 2 * NGRAPH * HID * sizeof(float), stream);  // first layer only; norm_coef re-zeroes

    bucket_count<<<1024, 256, 0, stream>>>(ei, E, flags, bcnt, NB);
    scan_buckets<<<1, 256, 0, stream>>>(bcnt, NB, E, gBase, gCursor, rowStart, N);
    bucket_scatter<<<1024, 256, 0, stream>>>(ei, E, flags, gCursor, binned, NB);
    bucket_sort<<<NB, 1024, 0, stream>>>(binned, gBase, csrSrc, rowStart, N);
    graph_cnt_k<<<(NGRAPH + 255) / 256, 256, 0, stream>>>(batch, N, gcnt);

    node_feat0<<<nbN, 256, 0, stream>>>(x, din0, flags, prm, hb, as_, ad_, N);

    for (int l = 0; l < 4; ++l) {
        const float* prmL = prm + l * 352;
        const float* prmNext = prm + (l + 1 < 4 ? (l + 1) * 352 : 0);

        gat_agg<<<nbN, 256, 0, stream>>>(rowStart, csrSrc, hb, as_, ad_, prmL, batch,
                                         tb, gsum, gsumsq, N);
        norm_coef<<<(NGRAPH * HID + 255) / 256, 256, 0, stream>>>(gsum, gsumsq, gcnt, prmL, gA, gB);
        norm_feat<<<nbN, 256, 0, stream>>>(tb, gA, gB, batch, xcur, N, l > 0 ? 1 : 0,
                                           l == 3 ? 1 : 0, prmNext, hb, as_, ad_, pooled);
    }

    final_lin<<<(NGRAPH + 255) / 256, 256, 0, stream>>>(pooled, gcnt, prm, flags, d_out);
}